// Round 16
// baseline (100.157 us; speedup 1.0000x reference)
//
#include <hip/hip_runtime.h>
#include <stdint.h>

// Problem constants
#define NN   4000      // nodes
#define EE   64000     // edges
#define KSEL 32000     // top-k
#define CAP  64        // per-src bucket capacity (mean selected degree = 8)
#define NBM  250       // rk_mark blocks

typedef __attribute__((ext_vector_type(8))) short bf16x8;
typedef __attribute__((ext_vector_type(4))) float f32x4;

// ---------------- workspace layout (bytes) ----------------
static constexpr size_t O_HIST1 = 0;                        // 4096*4
static constexpr size_t O_HIST2 = 16384;                    // 4096*4
static constexpr size_t O_META  = 32768;                    // 64*4  [2]=C1 [3]=C2 [6]=done-ctr
static constexpr size_t O_CNT   = 33024;                    // 4000*4
static constexpr size_t ZERO_BYTES = 49024;                 // zeroed inside rk_prep (12256 dwords)
static constexpr size_t O_BUCK  = 49024;                    // 4000*64*4 = 1024000
static constexpr size_t O_KEYS  = 1073024;                  // 64000*8
static constexpr size_t O_CAND  = 1585024;                  // 64000*4
static constexpr size_t O_CAND2 = 1841024;                  // 64000*4
static constexpr size_t O_MEANB = 2097024;                  // 4000*8 (f64)
static constexpr size_t O_BMAT  = 2129024;                  // 4000*64*4
static constexpr size_t O_V     = 3153024;                  // 4000*256*2 (bf16)
static constexpr size_t O_WALLT = 5201024;                  // 1088*256*2 (bf16, transposed)
static constexpr size_t O_WVT   = 5758080;                  // 256*256*2 (bf16, transposed)
static constexpr size_t O_WST   = 5889152;                  // 17*256*8 (f64, [c][i], c=16 -> wsum2)
static constexpr size_t O_BS1   = 5923968;                  // 16*8 (f64)
static constexpr size_t O_CB    = 5924096;                  // 64*4
static constexpr size_t O_CONST = 5924352;                  // 8 (f64)

__device__ __forceinline__ unsigned short f2b(float f) {  // f32 -> bf16 (RNE)
  union { float f; unsigned u; } v; v.f = f;
  const unsigned r = v.u + 0x7fffu + ((v.u >> 16) & 1u);
  return (unsigned short)(r >> 16);
}
__device__ __forceinline__ float b2f(unsigned short b) {
  return __uint_as_float(((unsigned)b) << 16);
}
__device__ __forceinline__ bf16x8 ld_cvt8(const float* __restrict__ p) {
  const float4 fa = *(const float4*)p;
  const float4 fb = *(const float4*)(p + 4);
  bf16x8 r;
  r[0] = (short)f2b(fa.x); r[1] = (short)f2b(fa.y);
  r[2] = (short)f2b(fa.z); r[3] = (short)f2b(fa.w);
  r[4] = (short)f2b(fb.x); r[5] = (short)f2b(fb.y);
  r[6] = (short)f2b(fb.z); r[7] = (short)f2b(fb.w);
  return r;
}

// per-block boundary-bin select over 4096 bins (256 threads x 16 bins).
__device__ __forceinline__ void block_select(const unsigned* __restrict__ hist,
                                             unsigned target, unsigned* sh,
                                             unsigned& pbin, unsigned& rem) {
  const int t = threadIdx.x;
  unsigned h[16];
  unsigned s = 0;
#pragma unroll
  for (int b = 0; b < 16; ++b) { h[b] = hist[t * 16 + b]; s += h[b]; }
  sh[t] = s;
  __syncthreads();
  for (int off = 1; off < 256; off <<= 1) {
    const unsigned a = (t + off < 256) ? sh[t + off] : 0u;
    __syncthreads();
    sh[t] += a;
    __syncthreads();
  }
  const unsigned mysuf = sh[t];
  const unsigned sufnext = (t < 255) ? sh[t + 1] : 0u;
  __syncthreads();
  if (mysuf >= target && sufnext < target) {
    unsigned cum = sufnext;
#pragma unroll
    for (int b = 15; b >= 0; --b) {
      const unsigned hv = h[b];
      if (cum + hv >= target) { sh[256] = (unsigned)(t * 16 + b); sh[257] = target - cum; break; }
      cum += hv;
    }
  }
  __syncthreads();
  pbin = sh[256]; rem = sh[257];
  __syncthreads();
}

// ---------------- K0: weight precontractions + bf16 transposed weights --------
__global__ void rk_prep(const float* __restrict__ W_inc, const float* __restrict__ p_t,
                        const float* __restrict__ b_inc, const float* __restrict__ W_value,
                        unsigned short* __restrict__ Wallt, unsigned short* __restrict__ Wvt,
                        double* __restrict__ WsT,
                        double* __restrict__ bs1, float* __restrict__ cb,
                        double* __restrict__ consts, unsigned* __restrict__ zws) {
  const int i = blockIdx.x;   // 0..255 (k index)
  const int l = threadIdx.x;  // 0..63
  const int gid = i * 64 + l;
  if (gid < (int)(ZERO_BYTES / 4)) zws[gid] = 0u;
  __shared__ double sred[64];
  const int base = i * 2048 + l * 32;
#pragma unroll
  for (int c = 0; c < 16; ++c)
    Wallt[(size_t)(l * 16 + c) * 256 + i] = f2b(W_inc[base + c]);
  double accP = 0.0;
#pragma unroll
  for (int c = 0; c < 16; ++c)
    accP += (double)W_inc[base + 16 + c] * (double)p_t[l * 16 + c];
  Wallt[(size_t)(1024 + l) * 256 + i] = f2b((float)accP);
#pragma unroll
  for (int j = 0; j < 4; ++j)
    Wvt[(size_t)(l * 4 + j) * 256 + i] = f2b(W_value[i * 256 + l * 4 + j]);
  sred[l] = accP;
  __syncthreads();
  if (l == 0) {
    double s = 0.0;
    for (int j = 0; j < 64; ++j) s += sred[j];
    WsT[16 * 256 + i] = s;                  // wsum2
  }
  if (l < 16) {
    double s = 0.0;
    for (int l2 = 0; l2 < 64; ++l2) s += (double)W_inc[i * 2048 + l2 * 32 + l];
    WsT[l * 256 + i] = s;                   // transposed: [c][i]
  }
  if (i == 0) {
    __syncthreads();
    if (l < 16) {
      double s = 0.0;
      for (int l2 = 0; l2 < 64; ++l2) s += (double)b_inc[l2 * 32 + l];
      bs1[l] = s;
    }
    double cbv = 0.0;
#pragma unroll
    for (int c = 0; c < 16; ++c)
      cbv += (double)p_t[l * 16 + c] * (double)b_inc[l * 32 + 16 + c];
    cb[l] = (float)cbv;
    sred[l] = cbv;
    __syncthreads();
    if (l == 0) {
      double s = 0.0;
      for (int j = 0; j < 64; ++j) s += sred[j];
      consts[0] = s;
    }
  }
}

// ---------------- K1: meanB — homogeneous, 1 node per wave -------------------
__global__ __launch_bounds__(256) void rk_meanB(
    const float* __restrict__ x, const float* __restrict__ mw,
    const double* __restrict__ WsT, const double* __restrict__ bs1,
    const double* __restrict__ consts, double* __restrict__ meanB) {
  __shared__ double wst[17 * 256];   // 34 KB
  const int t = threadIdx.x;
#pragma unroll
  for (int j = 0; j < 17; ++j) wst[j * 256 + t] = WsT[j * 256 + t];
  __syncthreads();
  const int lt = t & 63;
  const int n = blockIdx.x * 4 + (t >> 6);
  float xv[4];
#pragma unroll
  for (int rep = 0; rep < 4; ++rep) xv[rep] = x[n * 256 + lt + rep * 64];
  double mwv[16];
#pragma unroll
  for (int c = 0; c < 16; ++c) mwv[c] = (double)mw[n * 16 + c];
  double acc = 0.0;
#pragma unroll
  for (int rep = 0; rep < 4; ++rep) {
    const int i = lt + rep * 64;
    double wa0 = wst[16 * 256 + i], wa1 = 0.0, wa2 = 0.0, wa3 = 0.0;
#pragma unroll
    for (int c = 0; c < 16; c += 4) {
      wa0 += mwv[c + 0] * wst[(c + 0) * 256 + i];
      wa1 += mwv[c + 1] * wst[(c + 1) * 256 + i];
      wa2 += mwv[c + 2] * wst[(c + 2) * 256 + i];
      wa3 += mwv[c + 3] * wst[(c + 3) * 256 + i];
    }
    acc += (double)xv[rep] * ((wa0 + wa1) + (wa2 + wa3));
  }
  for (int off = 32; off > 0; off >>= 1) acc += __shfl_down(acc, off, 64);
  if (lt == 0) {
    double s = acc + consts[0];
#pragma unroll
    for (int c = 0; c < 16; ++c) s += mwv[c] * bs1[c];
    meanB[n] = s * (1.0 / 2048.0);
  }
}

// ---------------- K2: fused MFMA Bmat+V (blocks 0..499) | keys (500..749) ----
__global__ __launch_bounds__(256) void rk_bmatv_keys(
    const float* __restrict__ x, const float* __restrict__ mw,
    const unsigned short* __restrict__ Wallt, const unsigned short* __restrict__ Wvt,
    const float* __restrict__ b_inc, const float* __restrict__ cb,
    const float* __restrict__ b_value,
    float* __restrict__ Bmat, unsigned short* __restrict__ V,
    const int* __restrict__ ei, const float* __restrict__ ew,
    const double* __restrict__ meanB,
    unsigned long long* __restrict__ keys, unsigned* __restrict__ hist1) {
  __shared__ unsigned lh[4096];
  const int bid = blockIdx.x;
  const int t = threadIdx.x;
  if (bid < 500) {
    // ---- MFMA Bmat + V (inline f32->bf16 A-operand) ----
    const int wv = t >> 6, lane = t & 63;
    const int lr = lane & 15, kg = lane >> 4;
    const int n0 = (bid % 125) * 32;
    const int by = bid / 125;
    const int l0 = by * 16;            // Bmat l-quarter
    const int c0 = by * 64 + wv * 16;  // V column tile
    f32x4 acc[2][5] = {};
    f32x4 accv[2] = {};
    const float* ax0 = x + (size_t)(n0 + lr) * 256 + kg * 8;
    const float* ax1 = ax0 + 16 * 256;
    const unsigned short* bp[5];
#pragma unroll
    for (int j = 0; j < 4; ++j)
      bp[j] = Wallt + (size_t)((l0 + wv * 4 + j) * 16 + lr) * 256 + kg * 8;
    bp[4] = Wallt + (size_t)(1024 + l0 + lr) * 256 + kg * 8;
    const unsigned short* bpv = Wvt + (size_t)(c0 + lr) * 256 + kg * 8;
#pragma unroll
    for (int kk = 0; kk < 8; ++kk) {
      const bf16x8 a0 = ld_cvt8(ax0 + kk * 32);
      const bf16x8 a1 = ld_cvt8(ax1 + kk * 32);
#pragma unroll
      for (int j = 0; j < 5; ++j) {
        const bf16x8 b = *(const bf16x8*)(bp[j] + kk * 32);
        acc[0][j] = __builtin_amdgcn_mfma_f32_16x16x32_bf16(a0, b, acc[0][j], 0, 0, 0);
        acc[1][j] = __builtin_amdgcn_mfma_f32_16x16x32_bf16(a1, b, acc[1][j], 0, 0, 0);
      }
      const bf16x8 bv = *(const bf16x8*)(bpv + kk * 32);
      accv[0] = __builtin_amdgcn_mfma_f32_16x16x32_bf16(a0, bv, accv[0], 0, 0, 0);
      accv[1] = __builtin_amdgcn_mfma_f32_16x16x32_bf16(a1, bv, accv[1], 0, 0, 0);
    }
    const int c = lr, rg = kg;
#pragma unroll
    for (int rt = 0; rt < 2; ++rt) {
      const int rbase = n0 + rt * 16 + rg * 4;
      float mwv[4];
#pragma unroll
      for (int r = 0; r < 4; ++r) mwv[r] = mw[(rbase + r) * 16 + c];
#pragma unroll
      for (int j = 0; j < 4; ++j) {
        const int lj = l0 + wv * 4 + j;
        const float bi = b_inc[lj * 32 + c];
        const float cbl = cb[lj];
#pragma unroll
        for (int r = 0; r < 4; ++r) {
          float prod = (acc[rt][j][r] + bi) * mwv[r];
#pragma unroll
          for (int off = 1; off < 16; off <<= 1) prod += __shfl_xor(prod, off, 64);
          const float c2 = __shfl(acc[rt][4][r], (lane & 48) | (wv * 4 + j), 64);
          if (c == 0) Bmat[(rbase + r) * 64 + lj] = (prod + c2 + cbl) * (1.0f / 32.0f);
        }
      }
    }
    const float bv = b_value[c0 + c];
#pragma unroll
    for (int rt = 0; rt < 2; ++rt)
#pragma unroll
      for (int r = 0; r < 4; ++r) {
        const float val = fmaxf(accv[rt][r] + bv, 0.f);
        V[(size_t)(n0 + rt * 16 + rg * 4 + r) * 256 + c0 + c] = f2b(val);
      }
  } else {
    // ---- keys + LDS-privatized 12-bit histogram ----
#pragma unroll
    for (int i = 0; i < 16; ++i) lh[t + i * 256] = 0u;
    __syncthreads();
    const int e = (bid - 500) * 256 + t;
    const int dst = ei[EE + e];
    const double aew = (double)ew[e] * meanB[dst];
    const unsigned long long b = (unsigned long long)__double_as_longlong(aew);
    const unsigned long long s = (b & 0x8000000000000000ull) ? ~b : (b | 0x8000000000000000ull);
    keys[e] = s;
    atomicAdd(&lh[(unsigned)(s >> 52)], 1u);
    __syncthreads();
#pragma unroll
    for (int i = 0; i < 16; ++i) {
      const unsigned v = lh[t + i * 256];
      if (v) atomicAdd(&hist1[t + i * 256], v);
    }
  }
}

// ---------------- K3: mark1 + last-block m2t tail ----------------------------
// Each block: select1 (redundant), mark winners into buckets, boundary cands
// into cand[] + hist2. Then release-fence + done-counter; the LAST block
// acquire-fences and runs select2 + mark2 + exact tie rank itself.
__global__ __launch_bounds__(256) void rk_mark(
    const unsigned long long* __restrict__ keys, const int* __restrict__ ei,
    unsigned* __restrict__ meta, int* __restrict__ cand, int* __restrict__ cand2,
    unsigned* __restrict__ cnt, int* __restrict__ bucket,
    const unsigned* __restrict__ hist1, unsigned* __restrict__ hist2) {
  __shared__ unsigned sh[258];
  __shared__ unsigned lastFlag;
  const int t = threadIdx.x;
  unsigned p1, m1;
  block_select(hist1, (unsigned)KSEL, sh, p1, m1);
  const int e = blockIdx.x * 256 + t;
  {
    const unsigned long long k = keys[e];
    const unsigned b12 = (unsigned)(k >> 52);
    if (b12 > p1) {
      const int src = ei[e];
      const unsigned pos = atomicAdd(&cnt[src], 1u);
      bucket[src * CAP + pos] = e;
    } else if (b12 == p1) {
      const unsigned pos = atomicAdd(&meta[2], 1u);
      cand[pos] = e;
      atomicAdd(&hist2[(unsigned)(k >> 40) & 0xFFFu], 1u);
    }
  }
  // ---- last-block protocol ----
  __threadfence();   // release: cand/bucket stores visible before counter obs
  __syncthreads();
  if (t == 0) {
    const unsigned prev = __hip_atomic_fetch_add(&meta[6], 1u, __ATOMIC_ACQ_REL,
                                                 __HIP_MEMORY_SCOPE_AGENT);
    lastFlag = (prev == NBM - 1) ? 1u : 0u;
  }
  __syncthreads();
  if (!lastFlag) return;
  __threadfence();   // acquire: see all other blocks' cand/hist2/meta
  // ---- select2 over hist2 (atomic loads), 256 thr x 16 bins ----
  if (t == 0) { sh[256] = 0u; sh[257] = 0u; }
  unsigned h2[16];
  unsigned s2 = 0;
#pragma unroll
  for (int b = 0; b < 16; ++b) {
    h2[b] = __hip_atomic_load(&hist2[t * 16 + b], __ATOMIC_RELAXED,
                              __HIP_MEMORY_SCOPE_AGENT);
    s2 += h2[b];
  }
  sh[t] = s2;
  __syncthreads();
  for (int off = 1; off < 256; off <<= 1) {
    const unsigned a = (t + off < 256) ? sh[t + off] : 0u;
    __syncthreads();
    sh[t] += a;
    __syncthreads();
  }
  const unsigned mysuf = sh[t];
  const unsigned sufnext = (t < 255) ? sh[t + 1] : 0u;
  __syncthreads();
  if (mysuf >= m1 && sufnext < m1) {
    unsigned cum = sufnext;
#pragma unroll
    for (int b = 15; b >= 0; --b) {
      const unsigned hv = h2[b];
      if (cum + hv >= m1) { sh[256] = (unsigned)(t * 16 + b); sh[257] = m1 - cum; break; }
      cum += hv;
    }
  }
  __syncthreads();
  const unsigned p2 = sh[256], m2 = sh[257];
  // ---- mark2 over C1 candidates ----
  const int C1 = (int)__hip_atomic_load(&meta[2], __ATOMIC_ACQUIRE,
                                        __HIP_MEMORY_SCOPE_AGENT);
  for (int i = t; i < C1; i += 256) {
    const int e2 = cand[i];
    const unsigned d12 = (unsigned)(keys[e2] >> 40) & 0xFFFu;
    if (d12 > p2) {
      const int src = ei[e2];
      const unsigned pos = atomicAdd(&cnt[src], 1u);
      bucket[src * CAP + pos] = e2;
    } else if (d12 == p2) {
      const unsigned pos = atomicAdd(&meta[3], 1u);
      cand2[pos] = e2;
    }
  }
  __threadfence();
  __syncthreads();
  // ---- exact tie rank among residual candidates (same-block data) ----
  const int C2 = (int)meta[3];
  for (int i = t; i < C2; i += 256) {
    const int e_i = cand2[i];
    const unsigned long long k_i = keys[e_i];
    int r = 0;
    for (int j = 0; j < C2; ++j) {
      const int e_j = cand2[j];
      const unsigned long long k_j = keys[e_j];
      if (k_j > k_i || (k_j == k_i && e_j < e_i)) ++r;
    }
    if (r < (int)m2) {
      const int src = ei[e_i];
      const unsigned pos = atomicAdd(&cnt[src], 1u);
      bucket[src * CAP + pos] = e_i;
    }
  }
}

// ---------------- K4: per-node gather softmax + weighted V -------------------
__global__ void rk_out(const int* __restrict__ ei, const float* __restrict__ ew,
                       const unsigned* __restrict__ cnt, const int* __restrict__ bucket,
                       const float* __restrict__ Bmat, const unsigned short* __restrict__ V,
                       float* __restrict__ out) {
  const int n = blockIdx.x;
  const int t = threadIdx.x;      // 0..255
  const int l = t >> 2;           // 0..63
  __shared__ int   sdst[CAP];
  __shared__ float sew[CAP];
  const unsigned d = cnt[n];
  if (t < (int)d) {
    const int e = bucket[n * CAP + t];
    sdst[t] = ei[EE + e];
    sew[t] = ew[e];
  }
  __syncthreads();
  float s = 0.f, acc = 0.f;
  for (unsigned i = 0; i < d; ++i) {
    const int dst = sdst[i];
    const float p = __expf(Bmat[dst * 64 + l] * sew[i]);
    s += p;
    acc += p * b2f(V[(size_t)dst * 256 + t]);
  }
  out[(size_t)n * 256 + t] = acc / (s + 1e-16f);
}

extern "C" void kernel_launch(void* const* d_in, const int* in_sizes, int n_in,
                              void* d_out, int out_size, void* d_ws, size_t ws_size,
                              hipStream_t stream) {
  const float* x       = (const float*)d_in[0];
  const float* p_t     = (const float*)d_in[1];
  const int*   ei      = (const int*)d_in[2];
  const float* ew      = (const float*)d_in[3];
  const float* W_value = (const float*)d_in[4];
  const float* b_value = (const float*)d_in[5];
  const float* W_inc   = (const float*)d_in[6];
  const float* b_inc   = (const float*)d_in[7];
  const float* mw      = (const float*)d_in[8];
  float* out = (float*)d_out;
  char* ws = (char*)d_ws;

  unsigned*           hist1 = (unsigned*)(ws + O_HIST1);
  unsigned*           hist2 = (unsigned*)(ws + O_HIST2);
  unsigned*           meta  = (unsigned*)(ws + O_META);
  unsigned*           cnt   = (unsigned*)(ws + O_CNT);
  int*                buck  = (int*)(ws + O_BUCK);
  unsigned long long* keys  = (unsigned long long*)(ws + O_KEYS);
  int*                cand  = (int*)(ws + O_CAND);
  int*                cand2 = (int*)(ws + O_CAND2);
  double*             meanB = (double*)(ws + O_MEANB);
  float*              Bmat  = (float*)(ws + O_BMAT);
  unsigned short*     V     = (unsigned short*)(ws + O_V);
  unsigned short*     Wallt = (unsigned short*)(ws + O_WALLT);
  unsigned short*     Wvt   = (unsigned short*)(ws + O_WVT);
  double*             WsT   = (double*)(ws + O_WST);
  double*             bs1   = (double*)(ws + O_BS1);
  float*              cb    = (float*)(ws + O_CB);
  double*             cst   = (double*)(ws + O_CONST);

  rk_prep<<<256, 64, 0, stream>>>(W_inc, p_t, b_inc, W_value, Wallt, Wvt,
                                  WsT, bs1, cb, cst, (unsigned*)ws);
  rk_meanB<<<1000, 256, 0, stream>>>(x, mw, WsT, bs1, cst, meanB);
  rk_bmatv_keys<<<750, 256, 0, stream>>>(x, mw, Wallt, Wvt, b_inc, cb, b_value,
                                         Bmat, V, ei, ew, meanB, keys, hist1);
  rk_mark<<<NBM, 256, 0, stream>>>(keys, ei, meta, cand, cand2, cnt, buck,
                                   hist1, hist2);
  rk_out<<<NN, 256, 0, stream>>>(ei, ew, cnt, buck, Bmat, V, out);
}

// Round 17
// 71.106 us; speedup vs baseline: 1.4086x; 1.4086x over previous
//
#include <hip/hip_runtime.h>
#include <stdint.h>

// Problem constants
#define NN   4000      // nodes
#define EE   64000     // edges
#define KSEL 32000     // top-k
#define CAP  64        // per-src bucket capacity (mean selected degree = 8)

typedef __attribute__((ext_vector_type(8))) short bf16x8;
typedef __attribute__((ext_vector_type(4))) float f32x4;

// ---------------- workspace layout (bytes) ----------------
static constexpr size_t O_HIST1 = 0;                        // 4096*4
static constexpr size_t O_HIST2 = 16384;                    // 4096*4
static constexpr size_t O_META  = 32768;                    // 64*4  [0]=p1 [1]=m1 [2]=C1 [3]=C2
static constexpr size_t O_CNT   = 33024;                    // 4000*4
static constexpr size_t ZERO_BYTES = 49024;                 // zeroed inside rk_prep (12256 dwords)
static constexpr size_t O_BUCK  = 49024;                    // 4000*64*4 = 1024000
static constexpr size_t O_KEYS  = 1073024;                  // 64000*8
static constexpr size_t O_CAND  = 1585024;                  // 64000*4
static constexpr size_t O_CAND2 = 1841024;                  // 64000*4
static constexpr size_t O_MEANB = 2097024;                  // 4000*8 (f64)
static constexpr size_t O_BMAT  = 2129024;                  // 4000*64*4
static constexpr size_t O_V     = 3153024;                  // 4000*256*2 (bf16)
static constexpr size_t O_WALLT = 5201024;                  // 1088*256*2 (bf16, transposed)
static constexpr size_t O_WVT   = 5758080;                  // 256*256*2 (bf16, transposed)
static constexpr size_t O_WST   = 5889152;                  // 17*256*8 (f64, [c][i], c=16 -> wsum2)
static constexpr size_t O_BS1   = 5923968;                  // 16*8 (f64)
static constexpr size_t O_CB    = 5924096;                  // 64*4
static constexpr size_t O_CONST = 5924352;                  // 8 (f64)

__device__ __forceinline__ unsigned short f2b(float f) {  // f32 -> bf16 (RNE)
  union { float f; unsigned u; } v; v.f = f;
  const unsigned r = v.u + 0x7fffu + ((v.u >> 16) & 1u);
  return (unsigned short)(r >> 16);
}
__device__ __forceinline__ float b2f(unsigned short b) {
  return __uint_as_float(((unsigned)b) << 16);
}
__device__ __forceinline__ bf16x8 ld_cvt8(const float* __restrict__ p) {
  const float4 fa = *(const float4*)p;
  const float4 fb = *(const float4*)(p + 4);
  bf16x8 r;
  r[0] = (short)f2b(fa.x); r[1] = (short)f2b(fa.y);
  r[2] = (short)f2b(fa.z); r[3] = (short)f2b(fa.w);
  r[4] = (short)f2b(fb.x); r[5] = (short)f2b(fb.y);
  r[6] = (short)f2b(fb.z); r[7] = (short)f2b(fb.w);
  return r;
}

// per-block boundary-bin select over 4096 bins (256 threads x 16 bins).
__device__ __forceinline__ void block_select(const unsigned* __restrict__ hist,
                                             unsigned target, unsigned* sh,
                                             unsigned& pbin, unsigned& rem) {
  const int t = threadIdx.x;
  unsigned h[16];
  unsigned s = 0;
#pragma unroll
  for (int b = 0; b < 16; ++b) { h[b] = hist[t * 16 + b]; s += h[b]; }
  sh[t] = s;
  __syncthreads();
  for (int off = 1; off < 256; off <<= 1) {
    const unsigned a = (t + off < 256) ? sh[t + off] : 0u;
    __syncthreads();
    sh[t] += a;
    __syncthreads();
  }
  const unsigned mysuf = sh[t];
  const unsigned sufnext = (t < 255) ? sh[t + 1] : 0u;
  __syncthreads();
  if (mysuf >= target && sufnext < target) {
    unsigned cum = sufnext;
#pragma unroll
    for (int b = 15; b >= 0; --b) {
      const unsigned hv = h[b];
      if (cum + hv >= target) { sh[256] = (unsigned)(t * 16 + b); sh[257] = target - cum; break; }
      cum += hv;
    }
  }
  __syncthreads();
  pbin = sh[256]; rem = sh[257];
  __syncthreads();
}

// ---------------- K0: weight precontractions + bf16 transposed weights --------
__global__ void rk_prep(const float* __restrict__ W_inc, const float* __restrict__ p_t,
                        const float* __restrict__ b_inc, const float* __restrict__ W_value,
                        unsigned short* __restrict__ Wallt, unsigned short* __restrict__ Wvt,
                        double* __restrict__ WsT,
                        double* __restrict__ bs1, float* __restrict__ cb,
                        double* __restrict__ consts, unsigned* __restrict__ zws) {
  const int i = blockIdx.x;   // 0..255 (k index)
  const int l = threadIdx.x;  // 0..63
  const int gid = i * 64 + l;
  if (gid < (int)(ZERO_BYTES / 4)) zws[gid] = 0u;
  __shared__ double sred[64];
  const int base = i * 2048 + l * 32;
#pragma unroll
  for (int c = 0; c < 16; ++c)
    Wallt[(size_t)(l * 16 + c) * 256 + i] = f2b(W_inc[base + c]);
  double accP = 0.0;
#pragma unroll
  for (int c = 0; c < 16; ++c)
    accP += (double)W_inc[base + 16 + c] * (double)p_t[l * 16 + c];
  Wallt[(size_t)(1024 + l) * 256 + i] = f2b((float)accP);
#pragma unroll
  for (int j = 0; j < 4; ++j)
    Wvt[(size_t)(l * 4 + j) * 256 + i] = f2b(W_value[i * 256 + l * 4 + j]);
  sred[l] = accP;
  __syncthreads();
  if (l == 0) {
    double s = 0.0;
    for (int j = 0; j < 64; ++j) s += sred[j];
    WsT[16 * 256 + i] = s;                  // wsum2
  }
  if (l < 16) {
    double s = 0.0;
    for (int l2 = 0; l2 < 64; ++l2) s += (double)W_inc[i * 2048 + l2 * 32 + l];
    WsT[l * 256 + i] = s;                   // transposed: [c][i]
  }
  if (i == 0) {
    __syncthreads();
    if (l < 16) {
      double s = 0.0;
      for (int l2 = 0; l2 < 64; ++l2) s += (double)b_inc[l2 * 32 + l];
      bs1[l] = s;
    }
    double cbv = 0.0;
#pragma unroll
    for (int c = 0; c < 16; ++c)
      cbv += (double)p_t[l * 16 + c] * (double)b_inc[l * 32 + 16 + c];
    cb[l] = (float)cbv;
    sred[l] = cbv;
    __syncthreads();
    if (l == 0) {
      double s = 0.0;
      for (int j = 0; j < 64; ++j) s += sred[j];
      consts[0] = s;
    }
  }
}

// ---------------- K1: meanB — homogeneous, 1 node per wave -------------------
__global__ __launch_bounds__(256) void rk_meanB(
    const float* __restrict__ x, const float* __restrict__ mw,
    const double* __restrict__ WsT, const double* __restrict__ bs1,
    const double* __restrict__ consts, double* __restrict__ meanB) {
  __shared__ double wst[17 * 256];   // 34 KB
  const int t = threadIdx.x;
#pragma unroll
  for (int j = 0; j < 17; ++j) wst[j * 256 + t] = WsT[j * 256 + t];
  __syncthreads();
  const int lt = t & 63;
  const int n = blockIdx.x * 4 + (t >> 6);
  float xv[4];
#pragma unroll
  for (int rep = 0; rep < 4; ++rep) xv[rep] = x[n * 256 + lt + rep * 64];
  double mwv[16];
#pragma unroll
  for (int c = 0; c < 16; ++c) mwv[c] = (double)mw[n * 16 + c];
  double acc = 0.0;
#pragma unroll
  for (int rep = 0; rep < 4; ++rep) {
    const int i = lt + rep * 64;
    double wa0 = wst[16 * 256 + i], wa1 = 0.0, wa2 = 0.0, wa3 = 0.0;
#pragma unroll
    for (int c = 0; c < 16; c += 4) {
      wa0 += mwv[c + 0] * wst[(c + 0) * 256 + i];
      wa1 += mwv[c + 1] * wst[(c + 1) * 256 + i];
      wa2 += mwv[c + 2] * wst[(c + 2) * 256 + i];
      wa3 += mwv[c + 3] * wst[(c + 3) * 256 + i];
    }
    acc += (double)xv[rep] * ((wa0 + wa1) + (wa2 + wa3));
  }
  for (int off = 32; off > 0; off >>= 1) acc += __shfl_down(acc, off, 64);
  if (lt == 0) {
    double s = acc + consts[0];
#pragma unroll
    for (int c = 0; c < 16; ++c) s += mwv[c] * bs1[c];
    meanB[n] = s * (1.0 / 2048.0);
  }
}

// ---------------- K2: fused MFMA Bmat+V (blocks 0..499) | keys (500..749) ----
// Both halves are short and independent of each other: bmatv needs only
// rk_prep's weights; keys needs meanB. Fused to cut one dispatch boundary.
__global__ __launch_bounds__(256) void rk_bmatv_keys(
    const float* __restrict__ x, const float* __restrict__ mw,
    const unsigned short* __restrict__ Wallt, const unsigned short* __restrict__ Wvt,
    const float* __restrict__ b_inc, const float* __restrict__ cb,
    const float* __restrict__ b_value,
    float* __restrict__ Bmat, unsigned short* __restrict__ V,
    const int* __restrict__ ei, const float* __restrict__ ew,
    const double* __restrict__ meanB,
    unsigned long long* __restrict__ keys, unsigned* __restrict__ hist1) {
  __shared__ unsigned lh[4096];
  const int bid = blockIdx.x;
  const int t = threadIdx.x;
  if (bid < 500) {
    // ---- MFMA Bmat + V (inline f32->bf16 A-operand) ----
    const int wv = t >> 6, lane = t & 63;
    const int lr = lane & 15, kg = lane >> 4;
    const int n0 = (bid % 125) * 32;
    const int by = bid / 125;
    const int l0 = by * 16;            // Bmat l-quarter
    const int c0 = by * 64 + wv * 16;  // V column tile
    f32x4 acc[2][5] = {};
    f32x4 accv[2] = {};
    const float* ax0 = x + (size_t)(n0 + lr) * 256 + kg * 8;
    const float* ax1 = ax0 + 16 * 256;
    const unsigned short* bp[5];
#pragma unroll
    for (int j = 0; j < 4; ++j)
      bp[j] = Wallt + (size_t)((l0 + wv * 4 + j) * 16 + lr) * 256 + kg * 8;
    bp[4] = Wallt + (size_t)(1024 + l0 + lr) * 256 + kg * 8;
    const unsigned short* bpv = Wvt + (size_t)(c0 + lr) * 256 + kg * 8;
#pragma unroll
    for (int kk = 0; kk < 8; ++kk) {
      const bf16x8 a0 = ld_cvt8(ax0 + kk * 32);
      const bf16x8 a1 = ld_cvt8(ax1 + kk * 32);
#pragma unroll
      for (int j = 0; j < 5; ++j) {
        const bf16x8 b = *(const bf16x8*)(bp[j] + kk * 32);
        acc[0][j] = __builtin_amdgcn_mfma_f32_16x16x32_bf16(a0, b, acc[0][j], 0, 0, 0);
        acc[1][j] = __builtin_amdgcn_mfma_f32_16x16x32_bf16(a1, b, acc[1][j], 0, 0, 0);
      }
      const bf16x8 bv = *(const bf16x8*)(bpv + kk * 32);
      accv[0] = __builtin_amdgcn_mfma_f32_16x16x32_bf16(a0, bv, accv[0], 0, 0, 0);
      accv[1] = __builtin_amdgcn_mfma_f32_16x16x32_bf16(a1, bv, accv[1], 0, 0, 0);
    }
    const int c = lr, rg = kg;
#pragma unroll
    for (int rt = 0; rt < 2; ++rt) {
      const int rbase = n0 + rt * 16 + rg * 4;
      float mwv[4];
#pragma unroll
      for (int r = 0; r < 4; ++r) mwv[r] = mw[(rbase + r) * 16 + c];
#pragma unroll
      for (int j = 0; j < 4; ++j) {
        const int lj = l0 + wv * 4 + j;
        const float bi = b_inc[lj * 32 + c];
        const float cbl = cb[lj];
#pragma unroll
        for (int r = 0; r < 4; ++r) {
          float prod = (acc[rt][j][r] + bi) * mwv[r];
#pragma unroll
          for (int off = 1; off < 16; off <<= 1) prod += __shfl_xor(prod, off, 64);
          const float c2 = __shfl(acc[rt][4][r], (lane & 48) | (wv * 4 + j), 64);
          if (c == 0) Bmat[(rbase + r) * 64 + lj] = (prod + c2 + cbl) * (1.0f / 32.0f);
        }
      }
    }
    const float bv = b_value[c0 + c];
#pragma unroll
    for (int rt = 0; rt < 2; ++rt)
#pragma unroll
      for (int r = 0; r < 4; ++r) {
        const float val = fmaxf(accv[rt][r] + bv, 0.f);
        V[(size_t)(n0 + rt * 16 + rg * 4 + r) * 256 + c0 + c] = f2b(val);
      }
  } else {
    // ---- keys + LDS-privatized 12-bit histogram ----
#pragma unroll
    for (int i = 0; i < 16; ++i) lh[t + i * 256] = 0u;
    __syncthreads();
    const int e = (bid - 500) * 256 + t;
    const int dst = ei[EE + e];
    const double aew = (double)ew[e] * meanB[dst];
    const unsigned long long b = (unsigned long long)__double_as_longlong(aew);
    const unsigned long long s = (b & 0x8000000000000000ull) ? ~b : (b | 0x8000000000000000ull);
    keys[e] = s;
    atomicAdd(&lh[(unsigned)(s >> 52)], 1u);
    __syncthreads();
#pragma unroll
    for (int i = 0; i < 16; ++i) {
      const unsigned v = lh[t + i * 256];
      if (v) atomicAdd(&hist1[t + i * 256], v);
    }
  }
}

// ---------------- K3: mark1 — winners straight into per-src buckets ----------
__global__ void rk_mark1(const unsigned long long* __restrict__ keys, const int* __restrict__ ei,
                         unsigned* __restrict__ meta, int* __restrict__ cand,
                         unsigned* __restrict__ cnt, int* __restrict__ bucket,
                         const unsigned* __restrict__ hist1, unsigned* __restrict__ hist2) {
  __shared__ unsigned sh[258];
  unsigned p1, m1;
  block_select(hist1, (unsigned)KSEL, sh, p1, m1);
  if (blockIdx.x == 0 && threadIdx.x == 0) { meta[0] = p1; meta[1] = m1; }
  const int e = blockIdx.x * 256 + threadIdx.x;
  const unsigned long long k = keys[e];
  const unsigned b12 = (unsigned)(k >> 52);
  if (b12 > p1) {
    const int src = ei[e];
    const unsigned pos = atomicAdd(&cnt[src], 1u);
    bucket[src * CAP + pos] = e;
  } else if (b12 == p1) {
    const unsigned pos = atomicAdd(&meta[2], 1u);
    cand[pos] = e;
    atomicAdd(&hist2[(unsigned)(k >> 40) & 0xFFFu], 1u);
  }
}

// ---------------- K4: single-block select2 + mark2 + exact tie rank ----------
__global__ __launch_bounds__(1024) void rk_m2t(
    const unsigned long long* __restrict__ keys, const int* __restrict__ ei,
    unsigned* __restrict__ meta, const int* __restrict__ cand,
    int* __restrict__ cand2, unsigned* __restrict__ cnt, int* __restrict__ bucket,
    const unsigned* __restrict__ hist2) {
  __shared__ unsigned suf[1024];
  __shared__ unsigned sp[2];
  const int t = threadIdx.x;
  const unsigned m1 = meta[1];
  unsigned h[4];
  unsigned s = 0;
#pragma unroll
  for (int b = 0; b < 4; ++b) { h[b] = hist2[t * 4 + b]; s += h[b]; }
  suf[t] = s;
  __syncthreads();
  for (int off = 1; off < 1024; off <<= 1) {
    const unsigned a = (t + off < 1024) ? suf[t + off] : 0u;
    __syncthreads();
    suf[t] += a;
    __syncthreads();
  }
  const unsigned mysuf = suf[t];
  const unsigned sufnext = (t < 1023) ? suf[t + 1] : 0u;
  if (mysuf >= m1 && sufnext < m1) {
    unsigned cum = sufnext;
#pragma unroll
    for (int b = 3; b >= 0; --b) {
      const unsigned hv = h[b];
      if (cum + hv >= m1) { sp[0] = (unsigned)(t * 4 + b); sp[1] = m1 - cum; break; }
      cum += hv;
    }
  }
  __syncthreads();
  const unsigned p2 = sp[0], m2 = sp[1];
  const int C1 = (int)meta[2];
  for (int i = t; i < C1; i += 1024) {
    const int e = cand[i];
    const unsigned d12 = (unsigned)(keys[e] >> 40) & 0xFFFu;
    if (d12 > p2) {
      const int src = ei[e];
      const unsigned pos = atomicAdd(&cnt[src], 1u);
      bucket[src * CAP + pos] = e;
    } else if (d12 == p2) {
      const unsigned pos = atomicAdd(&meta[3], 1u);
      cand2[pos] = e;
    }
  }
  __threadfence();
  __syncthreads();
  const int C2 = (int)__hip_atomic_load(&meta[3], __ATOMIC_ACQUIRE, __HIP_MEMORY_SCOPE_AGENT);
  for (int i = t; i < C2; i += 1024) {
    const int e_i = cand2[i];
    const unsigned long long k_i = keys[e_i];
    int r = 0;
    for (int j = 0; j < C2; ++j) {
      const int e_j = cand2[j];
      const unsigned long long k_j = keys[e_j];
      if (k_j > k_i || (k_j == k_i && e_j < e_i)) ++r;
    }
    if (r < (int)m2) {
      const int src = ei[e_i];
      const unsigned pos = atomicAdd(&cnt[src], 1u);
      bucket[src * CAP + pos] = e_i;
    }
  }
}

// ---------------- K5: per-node gather softmax + weighted V -------------------
__global__ void rk_out(const int* __restrict__ ei, const float* __restrict__ ew,
                       const unsigned* __restrict__ cnt, const int* __restrict__ bucket,
                       const float* __restrict__ Bmat, const unsigned short* __restrict__ V,
                       float* __restrict__ out) {
  const int n = blockIdx.x;
  const int t = threadIdx.x;      // 0..255
  const int l = t >> 2;           // 0..63
  __shared__ int   sdst[CAP];
  __shared__ float sew[CAP];
  const unsigned d = cnt[n];
  if (t < (int)d) {
    const int e = bucket[n * CAP + t];
    sdst[t] = ei[EE + e];
    sew[t] = ew[e];
  }
  __syncthreads();
  float s = 0.f, acc = 0.f;
  for (unsigned i = 0; i < d; ++i) {
    const int dst = sdst[i];
    const float p = __expf(Bmat[dst * 64 + l] * sew[i]);
    s += p;
    acc += p * b2f(V[(size_t)dst * 256 + t]);
  }
  out[(size_t)n * 256 + t] = acc / (s + 1e-16f);
}

extern "C" void kernel_launch(void* const* d_in, const int* in_sizes, int n_in,
                              void* d_out, int out_size, void* d_ws, size_t ws_size,
                              hipStream_t stream) {
  const float* x       = (const float*)d_in[0];
  const float* p_t     = (const float*)d_in[1];
  const int*   ei      = (const int*)d_in[2];
  const float* ew      = (const float*)d_in[3];
  const float* W_value = (const float*)d_in[4];
  const float* b_value = (const float*)d_in[5];
  const float* W_inc   = (const float*)d_in[6];
  const float* b_inc   = (const float*)d_in[7];
  const float* mw      = (const float*)d_in[8];
  float* out = (float*)d_out;
  char* ws = (char*)d_ws;

  unsigned*           hist1 = (unsigned*)(ws + O_HIST1);
  unsigned*           hist2 = (unsigned*)(ws + O_HIST2);
  unsigned*           meta  = (unsigned*)(ws + O_META);
  unsigned*           cnt   = (unsigned*)(ws + O_CNT);
  int*                buck  = (int*)(ws + O_BUCK);
  unsigned long long* keys  = (unsigned long long*)(ws + O_KEYS);
  int*                cand  = (int*)(ws + O_CAND);
  int*                cand2 = (int*)(ws + O_CAND2);
  double*             meanB = (double*)(ws + O_MEANB);
  float*              Bmat  = (float*)(ws + O_BMAT);
  unsigned short*     V     = (unsigned short*)(ws + O_V);
  unsigned short*     Wallt = (unsigned short*)(ws + O_WALLT);
  unsigned short*     Wvt   = (unsigned short*)(ws + O_WVT);
  double*             WsT   = (double*)(ws + O_WST);
  double*             bs1   = (double*)(ws + O_BS1);
  float*              cb    = (float*)(ws + O_CB);
  double*             cst   = (double*)(ws + O_CONST);

  rk_prep<<<256, 64, 0, stream>>>(W_inc, p_t, b_inc, W_value, Wallt, Wvt,
                                  WsT, bs1, cb, cst, (unsigned*)ws);
  rk_meanB<<<1000, 256, 0, stream>>>(x, mw, WsT, bs1, cst, meanB);
  rk_bmatv_keys<<<750, 256, 0, stream>>>(x, mw, Wallt, Wvt, b_inc, cb, b_value,
                                         Bmat, V, ei, ew, meanB, keys, hist1);
  rk_mark1<<<250, 256, 0, stream>>>(keys, ei, meta, cand, cnt, buck, hist1, hist2);
  rk_m2t<<<1, 1024, 0, stream>>>(keys, ei, meta, cand, cand2, cnt, buck, hist2);
  rk_out<<<NN, 256, 0, stream>>>(ei, ew, cnt, buck, Bmat, V, out);
}